// Round 6
// baseline (383.442 us; speedup 1.0000x reference)
//
#include <hip/hip_runtime.h>

// HashGrid2D: out[i, :] = table[hash(positions[i]), :]
// hash = ((floor(x)*73856093) ^ (floor(y)*19349663)) & (2^19 - 1)
//
// R8 post-mortem: R0 (naive), R7 (LDS-staged sorted), R8 (sorted direct)
// all land at ~103us kernel -> the floor is the HBM side: 250MB write
// (40us) overlapped with ~110MB of table first-fetches whose ORDER is
// scattered 128B lines (DRAM-activate-bound ~1.5-2 TB/s => ~60us).
// Slicing minimized fetch VOLUME (126MB) but not fetch ORDER.
// R9: make table fetch sequential by construction.
//   - persistent co-resident grid: 768 blocks (3/CU via launch_bounds),
//     each owns <=6 chunks of 512 rows; all blocks march slices 0..15 in
//     rough lockstep (no global sync needed, co-residency guarantees it).
//   - during phase s, fire-and-forget global_load_lds prefetch of each
//     block's ~44KB share of slice s+1 into L2 (dest = dead LDS scratch,
//     never waited on). 96 blocks/XCD tile the 4MB slice; per-XCD share
//     rotation (+12*(bid&7)) makes XCDs first-touch different sub-regions
//     -> each table line leaves HBM ~once, sequentially; L3 dedups.
//   - gathers: R8's sorted dense 8-lane/row loop, now hitting warm L2;
//     stores direct + nt into per-chunk 64KB windows (L2-absorbed).
//   - zero barriers in the phase loop; 4 barriers total.

#define HASH_MASK ((1u << 19) - 1u)
#define SLICE_SHIFT 15            // 16 slices x 32K buckets x 128B = 4MB
#define NSLICE 16
#define BLOCK 512
#define CHUNK 512
#define GRID 768                  // 3 blocks/CU x 256 CUs, co-resident
#define KMAX 6                    // ceil(3907 chunks / 768 blocks)
#define SLICE_BYTES (4u << 20)
#define SHARE_BYTES 43680u        // ~4MB/96, 16B-aligned

typedef float vfloat2 __attribute__((ext_vector_type(2)));
typedef float vfloat4 __attribute__((ext_vector_type(4)));

__global__ __launch_bounds__(BLOCK, 6) void HashGrid2D_37383395344981_kernel(
    const vfloat2* __restrict__ pos,
    const vfloat4* __restrict__ table,   // HASH_SIZE x 8 vfloat4
    vfloat4* __restrict__ out,           // N x 8 vfloat4
    int n, int nchunks)
{
    __shared__ unsigned perm[KMAX][CHUNK];      // 12 KB
    __shared__ unsigned cnt[KMAX][NSLICE];
    __shared__ unsigned sbase[KMAX][NSLICE + 1];
    __shared__ unsigned scratch[256];           // dead prefetch dest (1KB)

    const int tid = threadIdx.x;
    const int bid = blockIdx.x;

    for (int i = tid; i < KMAX * NSLICE; i += BLOCK)
        ((unsigned*)cnt)[i] = 0u;
    __syncthreads();

    // Hash one row per thread per chunk; rank via LDS atomic.
    unsigned hv[KMAX], rk[KMAX];
#pragma unroll
    for (int k = 0; k < KMAX; ++k) {
        int c = k * GRID + bid;
        long long r = (long long)c * CHUNK + tid;
        hv[k] = 0xFFFFFFFFu;
        if (c < nchunks && r < n) {
            vfloat2 p = __builtin_nontemporal_load(&pos[r]);
            unsigned ix = (unsigned)(int)floorf(p.x);
            unsigned iy = (unsigned)(int)floorf(p.y);
            unsigned h = ((ix * 73856093u) ^ (iy * 19349663u)) & HASH_MASK;
            hv[k] = h;
            rk[k] = atomicAdd(&cnt[k][h >> SLICE_SHIFT], 1u);
        }
    }
    __syncthreads();

    if (tid < KMAX) {               // exclusive prefix per chunk
        unsigned acc = 0u;
#pragma unroll
        for (int s = 0; s < NSLICE; ++s) { sbase[tid][s] = acc; acc += cnt[tid][s]; }
        sbase[tid][NSLICE] = acc;
    }
    __syncthreads();

#pragma unroll
    for (int k = 0; k < KMAX; ++k)
        if (hv[k] != 0xFFFFFFFFu)
            perm[k][sbase[k][hv[k] >> SLICE_SHIFT] + rk[k]] =
                (hv[k] << 9) | (unsigned)tid;
    __syncthreads();

    const int cc = tid & 7;
    const int ri = tid >> 3;
    const char* tbytes = (const char*)table;

    for (unsigned s = 0; s < NSLICE; ++s) {
        // Fire-and-forget sequential prefetch of slice s+1 into this XCD's
        // L2. Dest is dead LDS scratch; never waited on, never read.
        if (s + 1 < NSLICE) {
            unsigned share = ((unsigned)(bid >> 3) + (unsigned)(bid & 7) * 12u) % 96u;
            size_t sb   = (size_t)(s + 1) * SLICE_BYTES;
            size_t off  = sb + (size_t)share * SHARE_BYTES;
            size_t send = sb + SLICE_BYTES;
            for (int it = 0; it < 6; ++it) {       // 6 x 8KB block-sweeps
                size_t a = off + (size_t)it * (BLOCK * 16) + (size_t)tid * 16;
                if (a + 16 <= send) {
                    __builtin_amdgcn_global_load_lds(
                        (const __attribute__((address_space(1))) unsigned*)(tbytes + a),
                        (__attribute__((address_space(3))) unsigned*)scratch,
                        16, 0, 0);
                }
            }
        }

        // Gather this slice's rows of all my chunks; direct nt store into
        // each chunk's contiguous 64KB out window.
#pragma unroll
        for (int k = 0; k < KMAX; ++k) {
            int c = k * GRID + bid;
            if (c >= nchunks) break;
            unsigned i1 = sbase[k][s + 1];
            size_t obase = (size_t)c * CHUNK * 8;
            for (unsigned i = sbase[k][s] + ri; i < i1; i += 64) {
                unsigned e = perm[k][i];
                unsigned hh = e >> 9;
                unsigned lr = e & 511u;
                vfloat4 v = table[(size_t)hh * 8 + cc];   // warm L2 window
                __builtin_nontemporal_store(v, &out[obase + (size_t)lr * 8 + cc]);
            }
        }
    }
}

extern "C" void kernel_launch(void* const* d_in, const int* in_sizes, int n_in,
                              void* d_out, int out_size, void* d_ws, size_t ws_size,
                              hipStream_t stream) {
    const vfloat2* pos   = (const vfloat2*)d_in[0];
    const vfloat4* table = (const vfloat4*)d_in[1];
    vfloat4* out = (vfloat4*)d_out;

    int n = in_sizes[0] / 2;
    int nchunks = (n + CHUNK - 1) / CHUNK;
    int grid = (nchunks < GRID) ? nchunks : GRID;

    HashGrid2D_37383395344981_kernel<<<grid, BLOCK, 0, stream>>>(pos, table, out, n, nchunks);
}